// Round 1
// 989.038 us; speedup vs baseline: 1.2205x; 1.2205x over previous
//
#include <hip/hip_runtime.h>
#include <hip/hip_bf16.h>

// Problem dims (fixed by reference): E=1e6, NN=50000, R=6, H=128, D=256, O=1, L=3
#define RR 6
#define HH 128
#define DD 256

typedef __attribute__((ext_vector_type(8))) short short8;
typedef __attribute__((ext_vector_type(4))) float floatx4;

__device__ __forceinline__ short f2bf(float f) {
    unsigned u = __builtin_bit_cast(unsigned, f);
    u += 0x7fffu + ((u >> 16) & 1u);   // RTN-even
    return (short)(u >> 16);
}
__device__ __forceinline__ float bf2f(short s) {
    unsigned u = ((unsigned)(unsigned short)s) << 16;
    return __builtin_bit_cast(float, u);
}

// LDS tile: 64 rows x 256 bf16 (512 B/row), XOR-swizzled so stride-512B
// fragment reads (16 lanes, same col, rows 0..15) spread across 8 bank-quads
// (2-way residual aliasing = free per m136). Swizzle bits 4..6 only, so any
// 16B-aligned chunk stays contiguous and 4B words map consistently.
__device__ __forceinline__ int swz(int row, int byte_in_row) {
    return row * 512 + (byte_in_row ^ ((row & 7) << 4));
}

// ---------------- f32 -> bf16 convert ----------------
__global__ __launch_bounds__(256) void conv_bf16(const float* __restrict__ in,
                                                 short* __restrict__ out, int count) {
    int i = blockIdx.x * 256 + threadIdx.x;
    if (i < count) out[i] = f2bf(in[i]);
}

// ---------------- CSR build: histogram + per-edge rank ----------------
// rank[e] = position of edge e within its node bucket (halves atomic count vs
// a second cursor-atomic pass: the atomicAdd return value IS the rank)
__global__ __launch_bounds__(256) void hist_rank(const int* __restrict__ idx,
                                                 int* __restrict__ counts,
                                                 int* __restrict__ rank, int E) {
    int i = blockIdx.x * 256 + threadIdx.x;
    if (i < E) rank[i] = atomicAdd(&counts[idx[i]], 1);
}

// ---------------- CSR build: exclusive scan over counts (single block) ----------------
__global__ __launch_bounds__(1024) void scan_kernel(const int* __restrict__ counts,
                                                    int* __restrict__ row_start,
                                                    int M, int E) {
    __shared__ int sdata[1024];
    int t = threadIdx.x;
    int chunk = (M + 1023) >> 10;
    int lo = t * chunk;
    int hi = lo + chunk; if (hi > M) hi = M;
    int s = 0;
    for (int i = lo; i < hi; i++) s += counts[i];
    sdata[t] = s;
    __syncthreads();
    for (int d = 1; d < 1024; d <<= 1) {
        int v = (t >= d) ? sdata[t - d] : 0;
        __syncthreads();
        sdata[t] += v;
        __syncthreads();
    }
    int base = (t == 0) ? 0 : sdata[t - 1];
    for (int i = lo; i < hi; i++) {
        row_start[i] = base;
        base += counts[i];
    }
    if (t == 0) row_start[M] = E;
}

// ---------------- CSR build: atomic-free scatter using precomputed ranks ----------------
__global__ __launch_bounds__(256) void build_csr_rank(const int* __restrict__ idx,
                                                      const int* __restrict__ rank,
                                                      const int* __restrict__ row_start,
                                                      int* __restrict__ elist, int E) {
    int i = blockIdx.x * 256 + threadIdx.x;
    if (i < E) elist[row_start[idx[i]] + rank[i]] = i;
}

// ---------------- gather: per-node segment sum of (rbf.W)*x, write bf16 ----------------
// one wave per node; lane handles channels 2*lane, 2*lane+1
__global__ __launch_bounds__(256) void gather_nodes(
    const float* __restrict__ x, const float* __restrict__ rbf,
    const int* __restrict__ elist, const int* __restrict__ row_start,
    const float* __restrict__ Wr, short* __restrict__ n_bf, int M) {
    int gtid = blockIdx.x * 256 + threadIdx.x;
    int wave = gtid >> 6;
    int lane = threadIdx.x & 63;
    if (wave >= M) return;
    int c0 = lane * 2;
    float w0[RR], w1[RR];
#pragma unroll
    for (int r = 0; r < RR; r++) {
        w0[r] = Wr[c0 * RR + r];
        w1[r] = Wr[(c0 + 1) * RR + r];
    }
    int start = row_start[wave];
    int end = row_start[wave + 1];
    float a0 = 0.f, a1 = 0.f;
    for (int j = start; j < end; j++) {
        int e = elist[j];
        const float* rb = rbf + (size_t)e * RR;
        float s0 = 0.f, s1 = 0.f;
#pragma unroll
        for (int r = 0; r < RR; r++) {
            float rv = rb[r];
            s0 += w0[r] * rv;
            s1 += w1[r] * rv;
        }
        const float2 xv = *(const float2*)(x + (size_t)e * HH + c0);
        a0 += s0 * xv.x;
        a1 += s1 * xv.y;
    }
    unsigned p = ((unsigned)(unsigned short)f2bf(a1) << 16) | (unsigned short)(unsigned)f2bf(a0);
    *(unsigned*)(n_bf + (size_t)wave * HH + c0) = p;
}

// ---------------- fused MLP epilogue: activation -> bf16 pairs -> swizzled LDS ----------------
// Lane pair (l, l^1) holds adjacent output cols (f, f+1): pack to one b32 word
// via shfl_xor; even lane stores rows r=0,1; odd lane rows r=2,3 (all static
// indices -> registers, rule #20).
template <int DO_SILU>
__device__ __forceinline__ void epilogue_store(
    char* dst, const floatx4 (&acc)[4][4], const float* __restrict__ bias,
    int n_base, int lane, int lrow, int quad) {
#pragma unroll
    for (int nt = 0; nt < 4; nt++) {
        int f = n_base + nt * 16 + lrow;
        float bv = bias[f];
#pragma unroll
        for (int mt = 0; mt < 4; mt++) {
            unsigned u[4];
#pragma unroll
            for (int r = 0; r < 4; r++) {
                float v = acc[mt][nt][r] + bv;
                if (DO_SILU) v = v / (1.f + __expf(-v));
                unsigned uu = (unsigned)(unsigned short)f2bf(v);
                unsigned oo = (unsigned)__shfl_xor((int)uu, 1);
                u[r] = (lane & 1) ? ((oo & 0xffffu) | (uu << 16))
                                  : ((uu & 0xffffu) | (oo << 16));
            }
            int fe = f & ~1;
            int rbase = (lane & 1) ? 2 : 0;
            unsigned wlo = (lane & 1) ? u[2] : u[0];
            unsigned whi = (lane & 1) ? u[3] : u[1];
            int rowA = mt * 16 + quad * 4 + rbase;
            *(unsigned*)(dst + swz(rowA, fe * 2)) = wlo;
            *(unsigned*)(dst + swz(rowA + 1, fe * 2)) = whi;
        }
    }
}

// ---------------- fused: up-proj + 3x (Linear+SiLU) + out-proj ----------------
// One block = 64 nodes. Activations live in LDS ping-pong (2 x 32 KB); they
// never touch global. W tiles read from global (hot in L2: 448 KB total,
// reused by all 782 blocks). Saves ~205 MB of h_a/h_b HBM/L2 round-trips and
// 4 kernel launches vs the previous 5-kernel chain.
__global__ __launch_bounds__(256) void fused_mlp(
    const short* __restrict__ A,      // n_bf [M,128] bf16
    const short* __restrict__ Wup,    // bf16 [256,128]
    const float* __restrict__ b_up,   // [256]
    const short* __restrict__ Wl,     // bf16 [3,256,256]
    const float* __restrict__ bs,     // [3,256]
    const float* __restrict__ Wout,   // [256]
    float* __restrict__ out, int M) {
    __shared__ char lds[2][64 * 512];   // exactly 64 KB -> 2 blocks/CU
    int m0 = blockIdx.x * 64;
    int wave = threadIdx.x >> 6;
    int lane = threadIdx.x & 63;
    int lrow = lane & 15;
    int quad = lane >> 4;
    int n_base = wave * 64;
    int koff = quad * 8;

    // ---- up-projection: K=128, A from global ----
    {
        floatx4 acc[4][4] = {};
#pragma unroll
        for (int ks = 0; ks < HH / 32; ks++) {
            int k = ks * 32 + koff;
            short8 a[4], b[4];
#pragma unroll
            for (int mt = 0; mt < 4; mt++) {
                int m = m0 + mt * 16 + lrow;
                if (m >= M) m = M - 1;  // clamp: safe read, final store is guarded
                a[mt] = *(const short8*)(A + (size_t)m * HH + k);
            }
#pragma unroll
            for (int nt = 0; nt < 4; nt++)
                b[nt] = *(const short8*)(Wup + (size_t)(n_base + nt * 16 + lrow) * HH + k);
#pragma unroll
            for (int mt = 0; mt < 4; mt++)
#pragma unroll
                for (int nt = 0; nt < 4; nt++)
                    acc[mt][nt] = __builtin_amdgcn_mfma_f32_16x16x32_bf16(a[mt], b[nt], acc[mt][nt], 0, 0, 0);
        }
        epilogue_store<0>(lds[0], acc, b_up, n_base, lane, lrow, quad);
    }
    __syncthreads();

    // ---- 3 hidden layers: K=256, A from LDS (swizzled), ping-pong ----
    int cur = 0;
#pragma unroll
    for (int l = 0; l < 3; l++) {
        floatx4 acc[4][4] = {};
        const short* W = Wl + (size_t)l * DD * DD;
        const char* src = lds[cur];
#pragma unroll
        for (int ks = 0; ks < DD / 32; ks++) {
            int kb = ks * 64 + quad * 16;   // byte offset of this lane's K-chunk
            int k = ks * 32 + koff;
            short8 a[4], b[4];
#pragma unroll
            for (int mt = 0; mt < 4; mt++)
                a[mt] = *(const short8*)(src + swz(mt * 16 + lrow, kb));
#pragma unroll
            for (int nt = 0; nt < 4; nt++)
                b[nt] = *(const short8*)(W + (size_t)(n_base + nt * 16 + lrow) * DD + k);
#pragma unroll
            for (int mt = 0; mt < 4; mt++)
#pragma unroll
                for (int nt = 0; nt < 4; nt++)
                    acc[mt][nt] = __builtin_amdgcn_mfma_f32_16x16x32_bf16(a[mt], b[nt], acc[mt][nt], 0, 0, 0);
        }
        epilogue_store<1>(lds[cur ^ 1], acc, bs + (size_t)l * DD, n_base, lane, lrow, quad);
        cur ^= 1;
        __syncthreads();
    }

    // ---- out-projection: out[m] = h[m] . Wout, straight from LDS ----
    {
        int row = wave * 16 + lrow;         // 4 waves x 16 rows = 64 rows
        float s = 0.f;
#pragma unroll
        for (int j = 0; j < 64; j += 8) {
            int col = quad * 64 + j;        // each quad covers 64 of 256 cols
            short8 hv = *(const short8*)(lds[cur] + swz(row, col * 2));
#pragma unroll
            for (int t = 0; t < 8; t++) s += bf2f(hv[t]) * Wout[col + t];
        }
        s += __shfl_down(s, 32);
        s += __shfl_down(s, 16);
        if (quad == 0) {
            int m = m0 + row;
            if (m < M) out[m] = s;
        }
    }
}

extern "C" void kernel_launch(void* const* d_in, const int* in_sizes, int n_in,
                              void* d_out, int out_size, void* d_ws, size_t ws_size,
                              hipStream_t stream) {
    const float* x     = (const float*)d_in[0];
    const float* rbf   = (const float*)d_in[1];
    const int*   idx   = (const int*)d_in[2];
    // d_in[3] = num_nodes (device scalar) — NN derived from out_size instead
    const float* W_rbf = (const float*)d_in[4];
    const float* W_up  = (const float*)d_in[5];
    const float* b_up  = (const float*)d_in[6];
    const float* Ws    = (const float*)d_in[7];
    const float* bs    = (const float*)d_in[8];
    const float* W_out = (const float*)d_in[9];

    const int E = in_sizes[0] / HH;   // 1,000,000
    const int M = out_size;           // NN = 50,000 (O == 1)

    char* ws = (char*)d_ws;
    size_t off = 0;
    int*   counts   = (int*)(ws + off); off += (size_t)M * 4;
    int*   row_start= (int*)(ws + off); off += (size_t)(M + 1) * 4;
    int*   rank     = (int*)(ws + off); off += (size_t)E * 4;
    int*   elist    = (int*)(ws + off); off += (size_t)E * 4;
    short* n_bf     = (short*)(ws + off); off += (size_t)M * HH * 2;
    short* wup_bf   = (short*)(ws + off); off += (size_t)DD * HH * 2;
    short* wl_bf    = (short*)(ws + off); off += (size_t)3 * DD * DD * 2;

    // zero the histogram (ws is poisoned 0xAA before every call)
    hipMemsetAsync(counts, 0, (size_t)M * 4, stream);

    // weight converts (tiny)
    conv_bf16<<<(DD * HH + 255) / 256, 256, 0, stream>>>(W_up, wup_bf, DD * HH);
    conv_bf16<<<(3 * DD * DD + 255) / 256, 256, 0, stream>>>(Ws, wl_bf, 3 * DD * DD);

    // CSR build: 1e6 atomics total (rank captured from hist pass; scatter is atomic-free)
    const int eblocks = (E + 255) / 256;
    hist_rank<<<eblocks, 256, 0, stream>>>(idx, counts, rank, E);
    scan_kernel<<<1, 1024, 0, stream>>>(counts, row_start, M, E);
    build_csr_rank<<<eblocks, 256, 0, stream>>>(idx, rank, row_start, elist, E);

    // gather: per-node edge reduction -> n_bf (BW floor: 512 MB x-read)
    gather_nodes<<<(M + 3) / 4, 256, 0, stream>>>(x, rbf, elist, row_start, W_rbf, n_bf, M);

    // fused up-proj + 3x(Linear+SiLU) + out-proj, activations resident in LDS
    const int gblocks = (M + 63) / 64;
    fused_mlp<<<gblocks, 256, 0, stream>>>(n_bf, wup_bf, b_up, wl_bf, bs, W_out,
                                           (float*)d_out, M);
}

// Round 2
// 914.792 us; speedup vs baseline: 1.3196x; 1.0812x over previous
//
#include <hip/hip_runtime.h>
#include <hip/hip_bf16.h>

// Problem dims (fixed by reference): E=1e6, NN=50000, R=6, H=128, D=256, O=1, L=3
#define RR 6
#define HH 128
#define DD 256

typedef __attribute__((ext_vector_type(8))) short short8;
typedef __attribute__((ext_vector_type(4))) float floatx4;
typedef __attribute__((ext_vector_type(2))) float floatx2;
typedef __attribute__((ext_vector_type(4))) int intx4;

__device__ __forceinline__ short f2bf(float f) {
    unsigned u = __builtin_bit_cast(unsigned, f);
    u += 0x7fffu + ((u >> 16) & 1u);   // RTN-even
    return (short)(u >> 16);
}
__device__ __forceinline__ float bf2f(short s) {
    unsigned u = ((unsigned)(unsigned short)s) << 16;
    return __builtin_bit_cast(float, u);
}

// LDS tile: 64 rows x 256 bf16 (512 B/row), XOR-swizzled so stride-512B
// fragment reads (16 lanes, same col, rows 0..15) spread across 8 bank-quads
// (2-way residual aliasing = free per m136). Swizzle bits 4..6 only, so any
// 16B-aligned chunk stays contiguous.
__device__ __forceinline__ int swz(int row, int byte_in_row) {
    return row * 512 + (byte_in_row ^ ((row & 7) << 4));
}

// ---------------- weight converts + counts zero, one launch ----------------
__global__ __launch_bounds__(256) void conv_weights(
    const float* __restrict__ Wup, short* __restrict__ wup,
    const float* __restrict__ Ws, short* __restrict__ wl,
    int* __restrict__ counts, int M) {
    int i = blockIdx.x * 256 + threadIdx.x;
    if (i < DD * HH) wup[i] = f2bf(Wup[i]);
    if (i < 3 * DD * DD) wl[i] = f2bf(Ws[i]);
    if (i < M) counts[i] = 0;
}

// ---------------- CSR build: histogram + per-edge rank (4 edges/thread) ----------------
// rank[e] = position of edge e within its node bucket (atomicAdd return IS the rank)
__global__ __launch_bounds__(256) void hist_rank(const int* __restrict__ idx,
                                                 int* __restrict__ counts,
                                                 int* __restrict__ rank, int E) {
    int i = (blockIdx.x * 256 + threadIdx.x) * 4;
    if (i + 3 < E) {
        intx4 v = *(const intx4*)(idx + i);
        int r0 = atomicAdd(&counts[v.x], 1);
        int r1 = atomicAdd(&counts[v.y], 1);
        int r2 = atomicAdd(&counts[v.z], 1);
        int r3 = atomicAdd(&counts[v.w], 1);
        intx4 r = {r0, r1, r2, r3};
        *(intx4*)(rank + i) = r;
    } else {
        for (int k = 0; k < 4; k++)
            if (i + k < E) rank[i + k] = atomicAdd(&counts[idx[i + k]], 1);
    }
}

// ---------------- CSR build: exclusive scan over counts (single block) ----------------
__global__ __launch_bounds__(1024) void scan_kernel(const int* __restrict__ counts,
                                                    int* __restrict__ row_start,
                                                    int M, int E) {
    __shared__ int sdata[1024];
    int t = threadIdx.x;
    int chunk = (M + 1023) >> 10;
    int lo = t * chunk;
    int hi = lo + chunk; if (hi > M) hi = M;
    int s = 0;
    for (int i = lo; i < hi; i++) s += counts[i];
    sdata[t] = s;
    __syncthreads();
    for (int d = 1; d < 1024; d <<= 1) {
        int v = (t >= d) ? sdata[t - d] : 0;
        __syncthreads();
        sdata[t] += v;
        __syncthreads();
    }
    int base = (t == 0) ? 0 : sdata[t - 1];
    for (int i = lo; i < hi; i++) {
        row_start[i] = base;
        base += counts[i];
    }
    if (t == 0) row_start[M] = E;
}

// ---------------- CSR build: atomic-free scatter using ranks (4 edges/thread) ----------------
__global__ __launch_bounds__(256) void build_csr_rank(const int* __restrict__ idx,
                                                      const int* __restrict__ rank,
                                                      const int* __restrict__ row_start,
                                                      int* __restrict__ elist, int E) {
    int i = (blockIdx.x * 256 + threadIdx.x) * 4;
    if (i + 3 < E) {
        intx4 v = *(const intx4*)(idx + i);
        intx4 r = *(const intx4*)(rank + i);
        elist[row_start[v.x] + r.x] = i;
        elist[row_start[v.y] + r.y] = i + 1;
        elist[row_start[v.z] + r.z] = i + 2;
        elist[row_start[v.w] + r.w] = i + 3;
    } else {
        for (int k = 0; k < 4; k++)
            if (i + k < E) elist[row_start[idx[i + k]] + rank[i + k]] = i + k;
    }
}

// ---------------- gather: per-node segment sum of (rbf.W)*x, write bf16 ----------------
// one wave per node; lane handles channels 2*lane, 2*lane+1.
// Edge id pulled to SGPR via readfirstlane -> rbf reads become scalar (s_load,
// constant cache), freeing the VMEM pipe for the 512B x-row loads. Manual
// 2-edge unroll overlaps two HBM row fetches.
__global__ __launch_bounds__(256) void gather_nodes(
    const float* __restrict__ x, const float* __restrict__ rbf,
    const int* __restrict__ elist, const int* __restrict__ row_start,
    const float* __restrict__ Wr, short* __restrict__ n_bf, int M) {
    int gtid = blockIdx.x * 256 + threadIdx.x;
    int wave = gtid >> 6;
    int lane = threadIdx.x & 63;
    if (wave >= M) return;
    int c0 = lane * 2;
    float w0[RR], w1[RR];
#pragma unroll
    for (int r = 0; r < RR; r++) {
        w0[r] = Wr[c0 * RR + r];
        w1[r] = Wr[(c0 + 1) * RR + r];
    }
    int start = __builtin_amdgcn_readfirstlane(row_start[wave]);
    int end = __builtin_amdgcn_readfirstlane(row_start[wave + 1]);
    float a0 = 0.f, a1 = 0.f;
    int j = start;
    for (; j + 2 <= end; j += 2) {
        int e0 = __builtin_amdgcn_readfirstlane(elist[j]);
        int e1 = __builtin_amdgcn_readfirstlane(elist[j + 1]);
        // issue both x-row loads first (independent HBM fetches overlap)
        floatx2 xv0 = __builtin_nontemporal_load((const floatx2*)(x + (size_t)e0 * HH + c0));
        floatx2 xv1 = __builtin_nontemporal_load((const floatx2*)(x + (size_t)e1 * HH + c0));
        const float* rb0 = rbf + (size_t)e0 * RR;
        const float* rb1 = rbf + (size_t)e1 * RR;
        float s00 = 0.f, s01 = 0.f, s10 = 0.f, s11 = 0.f;
#pragma unroll
        for (int r = 0; r < RR; r++) {
            float rv0 = rb0[r], rv1 = rb1[r];
            s00 += w0[r] * rv0;
            s01 += w1[r] * rv0;
            s10 += w0[r] * rv1;
            s11 += w1[r] * rv1;
        }
        a0 += s00 * xv0.x + s10 * xv1.x;
        a1 += s01 * xv0.y + s11 * xv1.y;
    }
    if (j < end) {
        int e = __builtin_amdgcn_readfirstlane(elist[j]);
        floatx2 xv = __builtin_nontemporal_load((const floatx2*)(x + (size_t)e * HH + c0));
        const float* rb = rbf + (size_t)e * RR;
        float s0 = 0.f, s1 = 0.f;
#pragma unroll
        for (int r = 0; r < RR; r++) {
            float rv = rb[r];
            s0 += w0[r] * rv;
            s1 += w1[r] * rv;
        }
        a0 += s0 * xv.x;
        a1 += s1 * xv.y;
    }
    unsigned p = ((unsigned)(unsigned short)f2bf(a1) << 16) | (unsigned short)(unsigned)f2bf(a0);
    *(unsigned*)(n_bf + (size_t)wave * HH + c0) = p;
}

// ---------------- fused MLP epilogue: activation -> bf16 pairs -> swizzled LDS ----------------
template <int DO_SILU>
__device__ __forceinline__ void epilogue_store(
    char* dst, const floatx4 (&acc)[4][4], const float* __restrict__ bias,
    int n_base, int lane, int lrow, int quad) {
#pragma unroll
    for (int nt = 0; nt < 4; nt++) {
        int f = n_base + nt * 16 + lrow;
        float bv = bias[f];
#pragma unroll
        for (int mt = 0; mt < 4; mt++) {
            unsigned u[4];
#pragma unroll
            for (int r = 0; r < 4; r++) {
                float v = acc[mt][nt][r] + bv;
                if (DO_SILU) v = v / (1.f + __expf(-v));
                unsigned uu = (unsigned)(unsigned short)f2bf(v);
                unsigned oo = (unsigned)__shfl_xor((int)uu, 1);
                u[r] = (lane & 1) ? ((oo & 0xffffu) | (uu << 16))
                                  : ((uu & 0xffffu) | (oo << 16));
            }
            int fe = f & ~1;
            int rbase = (lane & 1) ? 2 : 0;
            unsigned wlo = (lane & 1) ? u[2] : u[0];
            unsigned whi = (lane & 1) ? u[3] : u[1];
            int rowA = mt * 16 + quad * 4 + rbase;
            *(unsigned*)(dst + swz(rowA, fe * 2)) = wlo;
            *(unsigned*)(dst + swz(rowA + 1, fe * 2)) = whi;
        }
    }
}

// ---------------- fused: up-proj + 3x (Linear+SiLU) + out-proj ----------------
__global__ __launch_bounds__(256) void fused_mlp(
    const short* __restrict__ A,      // n_bf [M,128] bf16
    const short* __restrict__ Wup,    // bf16 [256,128]
    const float* __restrict__ b_up,   // [256]
    const short* __restrict__ Wl,     // bf16 [3,256,256]
    const float* __restrict__ bs,     // [3,256]
    const float* __restrict__ Wout,   // [256]
    float* __restrict__ out, int M) {
    __shared__ char lds[2][64 * 512];   // 64 KB -> 2 blocks/CU
    int m0 = blockIdx.x * 64;
    int wave = threadIdx.x >> 6;
    int lane = threadIdx.x & 63;
    int lrow = lane & 15;
    int quad = lane >> 4;
    int n_base = wave * 64;
    int koff = quad * 8;

    // ---- up-projection: K=128, A from global ----
    {
        floatx4 acc[4][4] = {};
#pragma unroll
        for (int ks = 0; ks < HH / 32; ks++) {
            int k = ks * 32 + koff;
            short8 a[4], b[4];
#pragma unroll
            for (int mt = 0; mt < 4; mt++) {
                int m = m0 + mt * 16 + lrow;
                if (m >= M) m = M - 1;  // clamp: safe read, final store is guarded
                a[mt] = *(const short8*)(A + (size_t)m * HH + k);
            }
#pragma unroll
            for (int nt = 0; nt < 4; nt++)
                b[nt] = *(const short8*)(Wup + (size_t)(n_base + nt * 16 + lrow) * HH + k);
#pragma unroll
            for (int mt = 0; mt < 4; mt++)
#pragma unroll
                for (int nt = 0; nt < 4; nt++)
                    acc[mt][nt] = __builtin_amdgcn_mfma_f32_16x16x32_bf16(a[mt], b[nt], acc[mt][nt], 0, 0, 0);
        }
        epilogue_store<0>(lds[0], acc, b_up, n_base, lane, lrow, quad);
    }
    __syncthreads();

    // ---- 3 hidden layers: K=256, A from LDS (swizzled), ping-pong ----
    int cur = 0;
#pragma unroll
    for (int l = 0; l < 3; l++) {
        floatx4 acc[4][4] = {};
        const short* W = Wl + (size_t)l * DD * DD;
        const char* src = lds[cur];
#pragma unroll
        for (int ks = 0; ks < DD / 32; ks++) {
            int kb = ks * 64 + quad * 16;   // byte offset of this lane's K-chunk
            int k = ks * 32 + koff;
            short8 a[4], b[4];
#pragma unroll
            for (int mt = 0; mt < 4; mt++)
                a[mt] = *(const short8*)(src + swz(mt * 16 + lrow, kb));
#pragma unroll
            for (int nt = 0; nt < 4; nt++)
                b[nt] = *(const short8*)(W + (size_t)(n_base + nt * 16 + lrow) * DD + k);
#pragma unroll
            for (int mt = 0; mt < 4; mt++)
#pragma unroll
                for (int nt = 0; nt < 4; nt++)
                    acc[mt][nt] = __builtin_amdgcn_mfma_f32_16x16x32_bf16(a[mt], b[nt], acc[mt][nt], 0, 0, 0);
        }
        epilogue_store<1>(lds[cur ^ 1], acc, bs + (size_t)l * DD, n_base, lane, lrow, quad);
        cur ^= 1;
        __syncthreads();
    }

    // ---- out-projection: out[m] = h[m] . Wout, straight from LDS ----
    {
        int row = wave * 16 + lrow;         // 4 waves x 16 rows = 64 rows
        float s = 0.f;
#pragma unroll
        for (int j = 0; j < 64; j += 8) {
            int col = quad * 64 + j;        // each quad covers 64 of 256 cols
            short8 hv = *(const short8*)(lds[cur] + swz(row, col * 2));
#pragma unroll
            for (int t = 0; t < 8; t++) s += bf2f(hv[t]) * Wout[col + t];
        }
        s += __shfl_down(s, 32);
        s += __shfl_down(s, 16);
        if (quad == 0) {
            int m = m0 + row;
            if (m < M) out[m] = s;
        }
    }
}

extern "C" void kernel_launch(void* const* d_in, const int* in_sizes, int n_in,
                              void* d_out, int out_size, void* d_ws, size_t ws_size,
                              hipStream_t stream) {
    const float* x     = (const float*)d_in[0];
    const float* rbf   = (const float*)d_in[1];
    const int*   idx   = (const int*)d_in[2];
    // d_in[3] = num_nodes (device scalar) — NN derived from out_size instead
    const float* W_rbf = (const float*)d_in[4];
    const float* W_up  = (const float*)d_in[5];
    const float* b_up  = (const float*)d_in[6];
    const float* Ws    = (const float*)d_in[7];
    const float* bs    = (const float*)d_in[8];
    const float* W_out = (const float*)d_in[9];

    const int E = in_sizes[0] / HH;   // 1,000,000
    const int M = out_size;           // NN = 50,000 (O == 1)

    char* ws = (char*)d_ws;
    size_t off = 0;
    int*   counts   = (int*)(ws + off); off += (size_t)M * 4;
    int*   row_start= (int*)(ws + off); off += (size_t)(M + 1) * 4;
    int*   rank     = (int*)(ws + off); off += (size_t)E * 4;
    int*   elist    = (int*)(ws + off); off += (size_t)E * 4;
    short* n_bf     = (short*)(ws + off); off += (size_t)M * HH * 2;
    short* wup_bf   = (short*)(ws + off); off += (size_t)DD * HH * 2;
    short* wl_bf    = (short*)(ws + off); off += (size_t)3 * DD * DD * 2;

    // weight converts + counts zero (replaces hipMemsetAsync + 2 conv launches)
    conv_weights<<<(3 * DD * DD + 255) / 256, 256, 0, stream>>>(W_up, wup_bf, Ws, wl_bf,
                                                                counts, M);

    // CSR build: 1e6 atomics total, 4 edges/thread
    const int e4blocks = (E / 4 + 255) / 256;
    hist_rank<<<e4blocks, 256, 0, stream>>>(idx, counts, rank, E);
    scan_kernel<<<1, 1024, 0, stream>>>(counts, row_start, M, E);
    build_csr_rank<<<e4blocks, 256, 0, stream>>>(idx, rank, row_start, elist, E);

    // gather: per-node edge reduction -> n_bf (BW floor: 512 MB x-read)
    gather_nodes<<<(M + 3) / 4, 256, 0, stream>>>(x, rbf, elist, row_start, W_rbf, n_bf, M);

    // fused up-proj + 3x(Linear+SiLU) + out-proj, activations resident in LDS
    const int gblocks = (M + 63) / 64;
    fused_mlp<<<gblocks, 256, 0, stream>>>(n_bf, wup_bf, b_up, wl_bf, bs, W_out,
                                           (float*)d_out, M);
}

// Round 4
// 904.318 us; speedup vs baseline: 1.3348x; 1.0116x over previous
//
#include <hip/hip_runtime.h>
#include <hip/hip_bf16.h>

// Problem dims (fixed by reference): E=1e6, NN=50000, R=6, H=128, D=256, O=1, L=3
#define RR 6
#define HH 128
#define DD 256

typedef __attribute__((ext_vector_type(8))) short short8;
typedef __attribute__((ext_vector_type(4))) float floatx4;
typedef __attribute__((ext_vector_type(2))) float floatx2;
typedef __attribute__((ext_vector_type(4))) int intx4;

__device__ __forceinline__ short f2bf(float f) {
    unsigned u = __builtin_bit_cast(unsigned, f);
    u += 0x7fffu + ((u >> 16) & 1u);   // RTN-even
    return (short)(u >> 16);
}
__device__ __forceinline__ float bf2f(short s) {
    unsigned u = ((unsigned)(unsigned short)s) << 16;
    return __builtin_bit_cast(float, u);
}

// LDS tile: 64 rows x 256 bf16 (512 B/row), XOR-swizzled so stride-512B
// fragment reads (16 lanes, same col, rows 0..15) spread across 8 bank-quads
// (2-way residual aliasing = free per m136). Swizzle bits 4..6 only, so any
// 16B-aligned chunk stays contiguous.
__device__ __forceinline__ int swz(int row, int byte_in_row) {
    return row * 512 + (byte_in_row ^ ((row & 7) << 4));
}

// readlane broadcast of a float held per-lane -> SGPR-resident float
__device__ __forceinline__ float rl_f(float v, int src) {
    return __builtin_bit_cast(float, __builtin_amdgcn_readlane(__builtin_bit_cast(int, v), src));
}

// ---------------- weight converts + counts zero, one launch ----------------
__global__ __launch_bounds__(256) void conv_weights(
    const float* __restrict__ Wup, short* __restrict__ wup,
    const float* __restrict__ Ws, short* __restrict__ wl,
    int* __restrict__ counts, int M) {
    int i = blockIdx.x * 256 + threadIdx.x;
    if (i < DD * HH) wup[i] = f2bf(Wup[i]);
    if (i < 3 * DD * DD) wl[i] = f2bf(Ws[i]);
    if (i < M) counts[i] = 0;
}

// ---------------- CSR build: histogram + per-edge rank (4 edges/thread) ----------------
// rank[e] = position of edge e within its node bucket (atomicAdd return IS the rank)
__global__ __launch_bounds__(256) void hist_rank(const int* __restrict__ idx,
                                                 int* __restrict__ counts,
                                                 int* __restrict__ rank, int E) {
    int i = (blockIdx.x * 256 + threadIdx.x) * 4;
    if (i + 3 < E) {
        intx4 v = *(const intx4*)(idx + i);
        int r0 = atomicAdd(&counts[v.x], 1);
        int r1 = atomicAdd(&counts[v.y], 1);
        int r2 = atomicAdd(&counts[v.z], 1);
        int r3 = atomicAdd(&counts[v.w], 1);
        intx4 r = {r0, r1, r2, r3};
        *(intx4*)(rank + i) = r;
    } else {
        for (int k = 0; k < 4; k++)
            if (i + k < E) rank[i + k] = atomicAdd(&counts[idx[i + k]], 1);
    }
}

// ---------------- CSR build: exclusive scan over counts (single block) ----------------
__global__ __launch_bounds__(1024) void scan_kernel(const int* __restrict__ counts,
                                                    int* __restrict__ row_start,
                                                    int M, int E) {
    __shared__ int sdata[1024];
    int t = threadIdx.x;
    int chunk = (M + 1023) >> 10;
    int lo = t * chunk;
    int hi = lo + chunk; if (hi > M) hi = M;
    int s = 0;
    for (int i = lo; i < hi; i++) s += counts[i];
    sdata[t] = s;
    __syncthreads();
    for (int d = 1; d < 1024; d <<= 1) {
        int v = (t >= d) ? sdata[t - d] : 0;
        __syncthreads();
        sdata[t] += v;
        __syncthreads();
    }
    int base = (t == 0) ? 0 : sdata[t - 1];
    for (int i = lo; i < hi; i++) {
        row_start[i] = base;
        base += counts[i];
    }
    if (t == 0) row_start[M] = E;
}

// ---------------- CSR build: atomic-free scatter using ranks (4 edges/thread) ----------------
__global__ __launch_bounds__(256) void build_csr_rank(const int* __restrict__ idx,
                                                      const int* __restrict__ rank,
                                                      const int* __restrict__ row_start,
                                                      int* __restrict__ elist, int E) {
    int i = (blockIdx.x * 256 + threadIdx.x) * 4;
    if (i + 3 < E) {
        intx4 v = *(const intx4*)(idx + i);
        intx4 r = *(const intx4*)(rank + i);
        elist[row_start[v.x] + r.x] = i;
        elist[row_start[v.y] + r.y] = i + 1;
        elist[row_start[v.z] + r.z] = i + 2;
        elist[row_start[v.w] + r.w] = i + 3;
    } else {
        for (int k = 0; k < 4; k++)
            if (i + k < E) elist[row_start[idx[i + k]] + rank[i + k]] = i + k;
    }
}

// ---------------- gather v2: per-node segment sum of (rbf.W)*x, write bf16 ----------------
// One wave per node; lane handles channels 2*lane, 2*lane+1.
// Key change vs v1: NO memory latency on the address path. Per 64-edge chunk,
// one coalesced vector load grabs all edge ids (lane-parallel) and 3 dwordx2
// loads prefetch each lane's edge's rbf row. The inner loop then broadcasts
// ids/rbf out of VGPRs via v_readlane (register file, no latency; lane index
// is wave-uniform so legalization is a single readfirstlane) and issues the
// 512B x-row loads 4-deep with nothing in front of them -> VMEM pipe stays
// saturated, gather becomes BW-bound instead of scalar-load-chain-bound.
__global__ __launch_bounds__(256) void gather_nodes(
    const float* __restrict__ x, const float* __restrict__ rbf,
    const int* __restrict__ elist, const int* __restrict__ row_start,
    const float* __restrict__ Wr, short* __restrict__ n_bf, int M) {
    int gtid = blockIdx.x * 256 + threadIdx.x;
    int wave = gtid >> 6;
    int lane = threadIdx.x & 63;
    if (wave >= M) return;
    int c0 = lane * 2;
    float w0[RR], w1[RR];
#pragma unroll
    for (int r = 0; r < RR; r++) {
        w0[r] = Wr[c0 * RR + r];
        w1[r] = Wr[(c0 + 1) * RR + r];
    }
    int start = row_start[wave];
    int end = row_start[wave + 1];
    float a0 = 0.f, a1 = 0.f;

    for (int base = start; base < end; base += 64) {
        int navail = end - base;
        if (navail > 64) navail = 64;
        // lane-parallel prefetch: edge ids (coalesced) + that edge's rbf row
        int jidx = base + lane;
        if (jidx >= end) jidx = end - 1;   // clamp: safe, tail masked below
        int vid = elist[jidx];
        const float* rbp = rbf + (size_t)vid * RR;
        floatx2 rb01 = *(const floatx2*)(rbp);
        floatx2 rb23 = *(const floatx2*)(rbp + 2);
        floatx2 rb45 = *(const floatx2*)(rbp + 4);

        for (int jj = 0; jj < navail; jj += 4) {
            // broadcast 4 edge ids from VGPR lanes (wave-uniform indices)
            int j0 = jj, j1 = jj + 1, j2 = jj + 2, j3 = jj + 3;
            int c1i = j1 < navail ? j1 : navail - 1;
            int c2i = j2 < navail ? j2 : navail - 1;
            int c3i = j3 < navail ? j3 : navail - 1;
            int e0 = __builtin_amdgcn_readlane(vid, j0);
            int e1 = __builtin_amdgcn_readlane(vid, c1i);
            int e2 = __builtin_amdgcn_readlane(vid, c2i);
            int e3 = __builtin_amdgcn_readlane(vid, c3i);
            // issue all 4 x-row loads back-to-back (4 x 512B in flight/wave)
            floatx2 xv0 = __builtin_nontemporal_load((const floatx2*)(x + (size_t)e0 * HH + c0));
            floatx2 xv1 = __builtin_nontemporal_load((const floatx2*)(x + (size_t)e1 * HH + c0));
            floatx2 xv2 = __builtin_nontemporal_load((const floatx2*)(x + (size_t)e2 * HH + c0));
            floatx2 xv3 = __builtin_nontemporal_load((const floatx2*)(x + (size_t)e3 * HH + c0));
            // per-edge scale from readlane'd rbf
            float m1 = j1 < navail ? 1.f : 0.f;
            float m2 = j2 < navail ? 1.f : 0.f;
            float m3 = j3 < navail ? 1.f : 0.f;
            float rv[4][RR];
            rv[0][0] = rl_f(rb01.x, j0);  rv[0][1] = rl_f(rb01.y, j0);
            rv[0][2] = rl_f(rb23.x, j0);  rv[0][3] = rl_f(rb23.y, j0);
            rv[0][4] = rl_f(rb45.x, j0);  rv[0][5] = rl_f(rb45.y, j0);
            rv[1][0] = rl_f(rb01.x, c1i); rv[1][1] = rl_f(rb01.y, c1i);
            rv[1][2] = rl_f(rb23.x, c1i); rv[1][3] = rl_f(rb23.y, c1i);
            rv[1][4] = rl_f(rb45.x, c1i); rv[1][5] = rl_f(rb45.y, c1i);
            rv[2][0] = rl_f(rb01.x, c2i); rv[2][1] = rl_f(rb01.y, c2i);
            rv[2][2] = rl_f(rb23.x, c2i); rv[2][3] = rl_f(rb23.y, c2i);
            rv[2][4] = rl_f(rb45.x, c2i); rv[2][5] = rl_f(rb45.y, c2i);
            rv[3][0] = rl_f(rb01.x, c3i); rv[3][1] = rl_f(rb01.y, c3i);
            rv[3][2] = rl_f(rb23.x, c3i); rv[3][3] = rl_f(rb23.y, c3i);
            rv[3][4] = rl_f(rb45.x, c3i); rv[3][5] = rl_f(rb45.y, c3i);
            float s00 = 0.f, s01 = 0.f, s10 = 0.f, s11 = 0.f;
            float s20 = 0.f, s21 = 0.f, s30 = 0.f, s31 = 0.f;
#pragma unroll
            for (int r = 0; r < RR; r++) {
                s00 += w0[r] * rv[0][r];  s01 += w1[r] * rv[0][r];
                s10 += w0[r] * rv[1][r];  s11 += w1[r] * rv[1][r];
                s20 += w0[r] * rv[2][r];  s21 += w1[r] * rv[2][r];
                s30 += w0[r] * rv[3][r];  s31 += w1[r] * rv[3][r];
            }
            s10 *= m1; s11 *= m1;
            s20 *= m2; s21 *= m2;
            s30 *= m3; s31 *= m3;
            a0 += s00 * xv0.x + s10 * xv1.x + s20 * xv2.x + s30 * xv3.x;
            a1 += s01 * xv0.y + s11 * xv1.y + s21 * xv2.y + s31 * xv3.y;
        }
    }
    unsigned p = ((unsigned)(unsigned short)f2bf(a1) << 16) | (unsigned short)(unsigned)f2bf(a0);
    *(unsigned*)(n_bf + (size_t)wave * HH + c0) = p;
}

// ---------------- fused MLP epilogue: activation -> bf16 pairs -> swizzled LDS ----------------
template <int DO_SILU>
__device__ __forceinline__ void epilogue_store(
    char* dst, const floatx4 (&acc)[4][4], const float* __restrict__ bias,
    int n_base, int lane, int lrow, int quad) {
#pragma unroll
    for (int nt = 0; nt < 4; nt++) {
        int f = n_base + nt * 16 + lrow;
        float bv = bias[f];
#pragma unroll
        for (int mt = 0; mt < 4; mt++) {
            unsigned u[4];
#pragma unroll
            for (int r = 0; r < 4; r++) {
                float v = acc[mt][nt][r] + bv;
                if (DO_SILU) v = v / (1.f + __expf(-v));
                unsigned uu = (unsigned)(unsigned short)f2bf(v);
                unsigned oo = (unsigned)__shfl_xor((int)uu, 1);
                u[r] = (lane & 1) ? ((oo & 0xffffu) | (uu << 16))
                                  : ((uu & 0xffffu) | (oo << 16));
            }
            int fe = f & ~1;
            int rbase = (lane & 1) ? 2 : 0;
            unsigned wlo = (lane & 1) ? u[2] : u[0];
            unsigned whi = (lane & 1) ? u[3] : u[1];
            int rowA = mt * 16 + quad * 4 + rbase;
            *(unsigned*)(dst + swz(rowA, fe * 2)) = wlo;
            *(unsigned*)(dst + swz(rowA + 1, fe * 2)) = whi;
        }
    }
}

// ---------------- fused: up-proj + 3x (Linear+SiLU) + out-proj ----------------
__global__ __launch_bounds__(256) void fused_mlp(
    const short* __restrict__ A,      // n_bf [M,128] bf16
    const short* __restrict__ Wup,    // bf16 [256,128]
    const float* __restrict__ b_up,   // [256]
    const short* __restrict__ Wl,     // bf16 [3,256,256]
    const float* __restrict__ bs,     // [3,256]
    const float* __restrict__ Wout,   // [256]
    float* __restrict__ out, int M) {
    __shared__ char lds[2][64 * 512];   // 64 KB -> 2 blocks/CU
    int m0 = blockIdx.x * 64;
    int wave = threadIdx.x >> 6;
    int lane = threadIdx.x & 63;
    int lrow = lane & 15;
    int quad = lane >> 4;
    int n_base = wave * 64;
    int koff = quad * 8;

    // ---- up-projection: K=128, A from global ----
    {
        floatx4 acc[4][4] = {};
#pragma unroll
        for (int ks = 0; ks < HH / 32; ks++) {
            int k = ks * 32 + koff;
            short8 a[4], b[4];
#pragma unroll
            for (int mt = 0; mt < 4; mt++) {
                int m = m0 + mt * 16 + lrow;
                if (m >= M) m = M - 1;  // clamp: safe read, final store is guarded
                a[mt] = *(const short8*)(A + (size_t)m * HH + k);
            }
#pragma unroll
            for (int nt = 0; nt < 4; nt++)
                b[nt] = *(const short8*)(Wup + (size_t)(n_base + nt * 16 + lrow) * HH + k);
#pragma unroll
            for (int mt = 0; mt < 4; mt++)
#pragma unroll
                for (int nt = 0; nt < 4; nt++)
                    acc[mt][nt] = __builtin_amdgcn_mfma_f32_16x16x32_bf16(a[mt], b[nt], acc[mt][nt], 0, 0, 0);
        }
        epilogue_store<0>(lds[0], acc, b_up, n_base, lane, lrow, quad);
    }
    __syncthreads();

    // ---- 3 hidden layers: K=256, A from LDS (swizzled), ping-pong ----
    int cur = 0;
#pragma unroll
    for (int l = 0; l < 3; l++) {
        floatx4 acc[4][4] = {};
        const short* W = Wl + (size_t)l * DD * DD;
        const char* src = lds[cur];
#pragma unroll
        for (int ks = 0; ks < DD / 32; ks++) {
            int kb = ks * 64 + quad * 16;   // byte offset of this lane's K-chunk
            int k = ks * 32 + koff;
            short8 a[4], b[4];
#pragma unroll
            for (int mt = 0; mt < 4; mt++)
                a[mt] = *(const short8*)(src + swz(mt * 16 + lrow, kb));
#pragma unroll
            for (int nt = 0; nt < 4; nt++)
                b[nt] = *(const short8*)(W + (size_t)(n_base + nt * 16 + lrow) * DD + k);
#pragma unroll
            for (int mt = 0; mt < 4; mt++)
#pragma unroll
                for (int nt = 0; nt < 4; nt++)
                    acc[mt][nt] = __builtin_amdgcn_mfma_f32_16x16x32_bf16(a[mt], b[nt], acc[mt][nt], 0, 0, 0);
        }
        epilogue_store<1>(lds[cur ^ 1], acc, bs + (size_t)l * DD, n_base, lane, lrow, quad);
        cur ^= 1;
        __syncthreads();
    }

    // ---- out-projection: out[m] = h[m] . Wout, straight from LDS ----
    {
        int row = wave * 16 + lrow;         // 4 waves x 16 rows = 64 rows
        float s = 0.f;
#pragma unroll
        for (int j = 0; j < 64; j += 8) {
            int col = quad * 64 + j;        // each quad covers 64 of 256 cols
            short8 hv = *(const short8*)(lds[cur] + swz(row, col * 2));
#pragma unroll
            for (int t = 0; t < 8; t++) s += bf2f(hv[t]) * Wout[col + t];
        }
        s += __shfl_down(s, 32);
        s += __shfl_down(s, 16);
        if (quad == 0) {
            int m = m0 + row;
            if (m < M) out[m] = s;
        }
    }
}

extern "C" void kernel_launch(void* const* d_in, const int* in_sizes, int n_in,
                              void* d_out, int out_size, void* d_ws, size_t ws_size,
                              hipStream_t stream) {
    const float* x     = (const float*)d_in[0];
    const float* rbf   = (const float*)d_in[1];
    const int*   idx   = (const int*)d_in[2];
    // d_in[3] = num_nodes (device scalar) — NN derived from out_size instead
    const float* W_rbf = (const float*)d_in[4];
    const float* W_up  = (const float*)d_in[5];
    const float* b_up  = (const float*)d_in[6];
    const float* Ws    = (const float*)d_in[7];
    const float* bs    = (const float*)d_in[8];
    const float* W_out = (const float*)d_in[9];

    const int E = in_sizes[0] / HH;   // 1,000,000
    const int M = out_size;           // NN = 50,000 (O == 1)

    char* ws = (char*)d_ws;
    size_t off = 0;
    int*   counts   = (int*)(ws + off); off += (size_t)M * 4;
    int*   row_start= (int*)(ws + off); off += (size_t)(M + 1) * 4;
    int*   rank     = (int*)(ws + off); off += (size_t)E * 4;
    int*   elist    = (int*)(ws + off); off += (size_t)E * 4;
    short* n_bf     = (short*)(ws + off); off += (size_t)M * HH * 2;
    short* wup_bf   = (short*)(ws + off); off += (size_t)DD * HH * 2;
    short* wl_bf    = (short*)(ws + off); off += (size_t)3 * DD * DD * 2;

    // weight converts + counts zero (replaces hipMemsetAsync + 2 conv launches)
    conv_weights<<<(3 * DD * DD + 255) / 256, 256, 0, stream>>>(W_up, wup_bf, Ws, wl_bf,
                                                                counts, M);

    // CSR build: 1e6 atomics total, 4 edges/thread
    const int e4blocks = (E / 4 + 255) / 256;
    hist_rank<<<e4blocks, 256, 0, stream>>>(idx, counts, rank, E);
    scan_kernel<<<1, 1024, 0, stream>>>(counts, row_start, M, E);
    build_csr_rank<<<e4blocks, 256, 0, stream>>>(idx, rank, row_start, elist, E);

    // gather v2: latency-decoupled per-node edge reduction -> n_bf
    gather_nodes<<<(M + 3) / 4, 256, 0, stream>>>(x, rbf, elist, row_start, W_rbf, n_bf, M);

    // fused up-proj + 3x(Linear+SiLU) + out-proj, activations resident in LDS
    const int gblocks = (M + 63) / 64;
    fused_mlp<<<gblocks, 256, 0, stream>>>(n_bf, wup_bf, b_up, wl_bf, bs, W_out,
                                           (float*)d_out, M);
}